// Round 3
// baseline (177.866 us; speedup 1.0000x reference)
//
#include <hip/hip_runtime.h>

// Problem constants (match reference).
#define CDIM 4096   // num_class
#define DDIM 512    // dim_label_emb
#define NPROD 16    // producer blocks (256 cols each -> 4096 cols)

// Math: mask = (u > 0.2f) ? 1.25f : 0.f; cumprod along rows => column j
// contributes co[k,j] * 1.25^(k+1) until the FIRST row k with u[k,j] <= 0.2,
// then exactly 0 forever (mask 0 kills the cumprod). scale *= 1.25f is the
// same f32 rounding sequence as jnp.cumprod, so w is bit-matched (absmax 0).
//
// Single fused launch:
//   blocks [0, NPROD):    producers — w[j] via per-wave ballot early-exit
//                         (expected ~40 live rows max over 64 cols), then
//                         release bit b of a single flag word (atomicOr).
//   blocks [NPROD, +512): consumers — copy label_emb row to out (output 0)
//                         FIRST (independent work, hides producer latency),
//                         then ONE lane polls the flag word with acquire
//                         LOADS (no RMW! round-2's RMW spin serialized at
//                         the TCC and cost ~46 us), then dot(row, w).
//
// Poison-safety: ws flag starts 0xAAAAAAAA; (v & 0xFFFF) == 0xFFFF only after
// all 16 producer ORs. Deadlock-safety: 528 blocks * 4 waves = 2112 waves
// << 8192 wave slots -> all co-resident; producers wait on nobody.
__global__ __launch_bounds__(256) void fused_kernel(
        const float* __restrict__ emb, const float* __restrict__ co,
        const float* __restrict__ mu, float* __restrict__ out,
        float* __restrict__ w, unsigned* __restrict__ flag) {
    const int tid = threadIdx.x;
    const int b = blockIdx.x;
    if (b < NPROD) {
        // ---- producer: 256 adjacent columns ----
        const int j = b * 256 + tid;
        float acc = 0.f, scale = 1.25f;   // scale = 1.25^(k+1) at row k
        bool alive = true;
        for (int k0 = 0; k0 < CDIM; k0 += 16) {   // 32 loads in flight
            float u[16], c[16];
#pragma unroll
            for (int i = 0; i < 16; ++i) {
                size_t off = (size_t)(k0 + i) * CDIM + j;
                u[i] = mu[off];
                c[i] = co[off];
            }
#pragma unroll
            for (int i = 0; i < 16; ++i) {
                if (alive) {
                    if (u[i] > 0.2f) { acc += c[i] * scale; scale *= 1.25f; }
                    else             { alive = false; }
                }
            }
            if (__ballot(alive) == 0ULL) break;   // whole wave's columns dead
        }
        w[j] = acc;
        __threadfence();          // each thread's w store -> agent-visible
        __syncthreads();          // whole block done + fenced
        if (tid == 0)
            __hip_atomic_fetch_or(flag, 1u << b, __ATOMIC_RELEASE,
                                  __HIP_MEMORY_SCOPE_AGENT);
    } else {
        // ---- consumer: one label_emb row ----
        const int d = b - NPROD;
        const float4* row  = (const float4*)(emb + (size_t)d * CDIM);
        float4*       orow = (float4*)(out + (size_t)d * CDIM);
        float4 v[4];
#pragma unroll
        for (int it = 0; it < 4; ++it) {          // copy first (output 0)
            int i = it * 256 + tid;
            v[it] = row[i];
            orow[i] = v[it];
        }
        // acquire: single lane, LOAD-only poll on one word (no RMW storm)
        if (tid == 0) {
            for (;;) {
                unsigned f = __hip_atomic_load(flag, __ATOMIC_ACQUIRE,
                                               __HIP_MEMORY_SCOPE_AGENT);
                if ((f & 0xFFFFu) == 0xFFFFu) break;
                __builtin_amdgcn_s_sleep(2);
            }
        }
        __syncthreads();          // rest of block waits on lane 0's acquire
        float acc = 0.f;
        const float4* w4 = (const float4*)w;
#pragma unroll
        for (int it = 0; it < 4; ++it) {
            int i = it * 256 + tid;
            float4 ww = w4[i];
            acc += v[it].x * ww.x + v[it].y * ww.y + v[it].z * ww.z + v[it].w * ww.w;
        }
#pragma unroll
        for (int off = 32; off > 0; off >>= 1) acc += __shfl_down(acc, off, 64);
        __shared__ float part[4];
        int lane = tid & 63, wv = tid >> 6;
        if (lane == 0) part[wv] = acc;
        __syncthreads();
        if (tid == 0)
            out[(size_t)DDIM * CDIM + d] = part[0] + part[1] + part[2] + part[3];
    }
}

extern "C" void kernel_launch(void* const* d_in, const int* in_sizes, int n_in,
                              void* d_out, int out_size, void* d_ws, size_t ws_size,
                              hipStream_t stream) {
    const float* label_emb = (const float*)d_in[0];   // (D, C)
    const float* co        = (const float*)d_in[1];   // (C, C)
    const float* mu        = (const float*)d_in[2];   // (C, C)
    float* out = (float*)d_out;                       // [D*C copy | D dim_emb]
    float* w   = (float*)d_ws;                        // C floats
    unsigned* flag = (unsigned*)((char*)d_ws + CDIM * sizeof(float));

    fused_kernel<<<NPROD + DDIM, 256, 0, stream>>>(label_emb, co, mu, out, w, flag);
}

// Round 4
// 147.049 us; speedup vs baseline: 1.2096x; 1.2096x over previous
//
#include <hip/hip_runtime.h>

// Problem constants (match reference).
#define CDIM 4096   // num_class
#define DDIM 512    // dim_label_emb
#define NPROD 16    // producer blocks; STRIPE columns each
#define STRIPE (CDIM / NPROD)   // 256

// Math: mask = (u > 0.2f) ? 1.25f : 0.f; cumprod along rows => column j
// contributes co[k,j] * 1.25^(k+1) until the FIRST row k with u[k,j] <= 0.2,
// then exactly 0 forever. scale *= 1.25f reproduces jnp.cumprod's f32
// rounding exactly (mask values are exactly {0, 1.25f}).
//
// ZERO inter-block sync (rounds 2-3 showed any cross-block wait costs
// 40-60 us here; everything is L3-resident so the kernel is latency-bound):
//   blocks [0,16):    compute w for a 256-col stripe (ballot early-exit,
//                     ~2 rounds of 16), stash w in LDS, then each thread
//                     dots rows d=tid, tid+256 against the stripe and
//                     atomicAdd's the partial into out1[d]. 16 adds per
//                     address -> negligible contention; float reorder noise
//                     ~1e-2 vs threshold 2037. Poison offset on out1
//                     (0xAAAAAAAA = -3.03e-13) is likewise negligible.
//   blocks [16,528):  pure copy of one label_emb row (output 0).
__global__ __launch_bounds__(256) void fused_kernel(
        const float* __restrict__ emb, const float* __restrict__ co,
        const float* __restrict__ mu, float* __restrict__ out) {
    const int tid = threadIdx.x;
    const int b = blockIdx.x;
    if (b < NPROD) {
        // ---- w for columns [j0, j0+STRIPE) ----
        const int j0 = b * STRIPE;
        const int j = j0 + tid;
        float acc = 0.f, scale = 1.25f;   // scale = 1.25^(k+1) at row k
        bool alive = true;
        for (int k0 = 0; k0 < CDIM; k0 += 16) {   // 32 loads in flight
            float u[16], c[16];
#pragma unroll
            for (int i = 0; i < 16; ++i) {
                size_t off = (size_t)(k0 + i) * CDIM + j;
                u[i] = mu[off];
                c[i] = co[off];
            }
#pragma unroll
            for (int i = 0; i < 16; ++i) {
                if (alive) {
                    if (u[i] > 0.2f) { acc += c[i] * scale; scale *= 1.25f; }
                    else             { alive = false; }
                }
            }
            if (__ballot(alive) == 0ULL) break;   // whole wave's columns dead
        }
        __shared__ float wlds[STRIPE];
        wlds[tid] = acc;
        __syncthreads();
        // ---- stripe-partial dot for all 512 rows, 2 rows per thread ----
        const float4* w4 = (const float4*)wlds;   // same-addr LDS broadcast
        float* out1 = out + (size_t)DDIM * CDIM;
#pragma unroll
        for (int half = 0; half < 2; ++half) {
            const int d = half * 256 + tid;
            const float4* rowp = (const float4*)(emb + (size_t)d * CDIM + j0);
            float dacc = 0.f;
#pragma unroll 8
            for (int i = 0; i < STRIPE / 4; ++i) {
                float4 e  = rowp[i];   // per-thread sequential; L1-friendly
                float4 ww = w4[i];
                dacc += e.x * ww.x + e.y * ww.y + e.z * ww.z + e.w * ww.w;
            }
            atomicAdd(&out1[d], dacc);
        }
    } else {
        // ---- pure copy of one label_emb row (output 0) ----
        const int d = b - NPROD;
        const float4* row  = (const float4*)(emb + (size_t)d * CDIM);
        float4*       orow = (float4*)(out + (size_t)d * CDIM);
#pragma unroll
        for (int it = 0; it < 4; ++it) {
            int i = it * 256 + tid;
            orow[i] = row[i];
        }
    }
}

extern "C" void kernel_launch(void* const* d_in, const int* in_sizes, int n_in,
                              void* d_out, int out_size, void* d_ws, size_t ws_size,
                              hipStream_t stream) {
    const float* label_emb = (const float*)d_in[0];   // (D, C)
    const float* co        = (const float*)d_in[1];   // (C, C)
    const float* mu        = (const float*)d_in[2];   // (C, C)
    float* out = (float*)d_out;                       // [D*C copy | D dim_emb]
    (void)d_ws; (void)ws_size;                        // workspace unused

    fused_kernel<<<NPROD + DDIM, 256, 0, stream>>>(label_emb, co, mu, out);
}

// Round 5
// 132.807 us; speedup vs baseline: 1.3393x; 1.1072x over previous
//
#include <hip/hip_runtime.h>

// Problem constants (match reference).
#define CDIM 4096   // num_class
#define DDIM 512    // dim_label_emb

// Math: mask = (u > 0.2f) ? 1.25f : 0.f; cumprod along rows => column j
// contributes co[k,j] * 1.25^(k+1) until the FIRST row k with u[k,j] <= 0.2,
// then exactly 0 forever. scale *= 1.25f reproduces jnp.cumprod's f32
// rounding exactly (mask values are exactly {0, 1.25f}) -> absmax 0.
//
// Two kernels, zero inter-block sync (graph edge orders them):
//  - Rounds 2/3 proved ANY cross-block wait costs 40-60 us here.
//  - Round 4 proved the producer-side dot (lane-per-row) is a 64-line/wave
//    scatter: ~13 us straggle on 16 CUs. Block-per-row coalesced dot (K2)
//    is the right shape.

// K1: w[j] for 64 columns per block, one wave per block -> 64 CUs in
// parallel, ballot early-exit at wave granularity (expected ~2 rounds of 16).
__global__ __launch_bounds__(64) void w_kernel(
        const float* __restrict__ co, const float* __restrict__ mu,
        float* __restrict__ w) {
    const int j = blockIdx.x * 64 + threadIdx.x;
    float acc = 0.f, scale = 1.25f;   // scale = 1.25^(k+1) at row k
    bool alive = true;
    for (int k0 = 0; k0 < CDIM; k0 += 16) {   // 32 loads in flight
        float u[16], c[16];
#pragma unroll
        for (int i = 0; i < 16; ++i) {
            size_t off = (size_t)(k0 + i) * CDIM + j;
            u[i] = mu[off];
            c[i] = co[off];
        }
#pragma unroll
        for (int i = 0; i < 16; ++i) {
            if (alive) {
                if (u[i] > 0.2f) { acc += c[i] * scale; scale *= 1.25f; }
                else             { alive = false; }
            }
        }
        if (__ballot(alive) == 0ULL) break;   // all 64 cols of this wave dead
    }
    w[j] = acc;
}

// K2: block per row — coalesced float4 read of the row (once), write the
// copy (output 0), accumulate dot vs w, wave+LDS reduce -> out1[d].
__global__ __launch_bounds__(256) void dot_copy_kernel(
        const float* __restrict__ emb, const float* __restrict__ w,
        float* __restrict__ out) {
    const int d = blockIdx.x;
    const int tid = threadIdx.x;
    const float4* row  = (const float4*)(emb + (size_t)d * CDIM);
    float4*       orow = (float4*)(out + (size_t)d * CDIM);
    const float4* w4   = (const float4*)w;
    float acc = 0.f;
#pragma unroll
    for (int it = 0; it < (CDIM / 4) / 256; ++it) {   // 4 iters
        int i = it * 256 + tid;
        float4 v  = row[i];
        float4 ww = w4[i];
        orow[i] = v;                       // output 0: pass-through copy
        acc += v.x * ww.x + v.y * ww.y + v.z * ww.z + v.w * ww.w;
    }
#pragma unroll
    for (int off = 32; off > 0; off >>= 1) acc += __shfl_down(acc, off, 64);
    __shared__ float part[4];
    int lane = tid & 63, wv = tid >> 6;
    if (lane == 0) part[wv] = acc;
    __syncthreads();
    if (tid == 0)
        out[(size_t)DDIM * CDIM + d] = part[0] + part[1] + part[2] + part[3];
}

extern "C" void kernel_launch(void* const* d_in, const int* in_sizes, int n_in,
                              void* d_out, int out_size, void* d_ws, size_t ws_size,
                              hipStream_t stream) {
    const float* label_emb = (const float*)d_in[0];   // (D, C)
    const float* co        = (const float*)d_in[1];   // (C, C)
    const float* mu        = (const float*)d_in[2];   // (C, C)
    float* out = (float*)d_out;                       // [D*C copy | D dim_emb]
    float* w   = (float*)d_ws;                        // C floats scratch

    w_kernel<<<CDIM / 64, 64, 0, stream>>>(co, mu, w);
    dot_copy_kernel<<<DDIM, 256, 0, stream>>>(label_emb, w, out);
}